// Round 1
// baseline (4311.497 us; speedup 1.0000x reference)
//
#include <hip/hip_runtime.h>
#include <math.h>

namespace {

constexpr int kB    = 64;
constexpr int kN    = 16384;
constexpr int kK    = 16;
constexpr int kNPT  = 16;     // points per thread
constexpr int kTH   = 1024;   // threads per block
constexpr int kWAVES = 16;

// ---------- exact (no-FMA) squared distance, matching XLA's sub/mul/add order ----------
__device__ __forceinline__ float dist2nc(float ax, float ay, float az,
                                         float bx, float by, float bz) {
#pragma clang fp contract(off)
  float dx = ax - bx;
  float dy = ay - by;
  float dz = az - bz;
  float s2 = dx * dx + dy * dy;
  return s2 + dz * dz;
}

// ---------- LAPACK helper ports (fp32) ----------
__device__ __forceinline__ float lapy2f(float x, float y) {
  float xa = fabsf(x), ya = fabsf(y);
  float w = fmaxf(xa, ya), z = fminf(xa, ya);
  if (z == 0.0f) return w;
  float t = z / w;
  return w * sqrtf(1.0f + t * t);
}

// LAPACK >= 3.10 slartg convention: c = |f|/r >= 0, r = sign(f)*hypot
__device__ __forceinline__ void lartgf(float f, float g, float* cs, float* sn, float* r) {
  if (g == 0.0f) { *cs = 1.0f; *sn = 0.0f; *r = f; }
  else if (f == 0.0f) { *cs = 0.0f; *sn = copysignf(1.0f, g); *r = fabsf(g); }
  else {
    float d = sqrtf(f * f + g * g);
    float p = 1.0f / d;
    *cs = fabsf(f) * p;
    *sn = g * copysignf(p, f);
    *r  = copysignf(d, f);
  }
}

// slaev2: eigen decomposition of [[a,b],[b,c]]; rt1 >= rt2, (cs1,sn1) for rt1
__device__ void laev2f(float a, float b, float c,
                       float* rt1, float* rt2, float* cs1, float* sn1) {
  float sm = a + c, df = a - c;
  float adf = fabsf(df), tb = b + b, ab = fabsf(tb);
  float acmx, acmn;
  if (fabsf(a) > fabsf(c)) { acmx = a; acmn = c; } else { acmx = c; acmn = a; }
  float rt;
  if (adf > ab)      { float t = ab / adf; rt = adf * sqrtf(1.0f + t * t); }
  else if (adf < ab) { float t = adf / ab; rt = ab * sqrtf(1.0f + t * t); }
  else               { rt = ab * sqrtf(2.0f); }
  int sgn1;
  if (sm < 0.0f) {
    *rt1 = 0.5f * (sm - rt); sgn1 = -1;
    *rt2 = (acmx / (*rt1)) * acmn - (b / (*rt1)) * b;
  } else if (sm > 0.0f) {
    *rt1 = 0.5f * (sm + rt); sgn1 = 1;
    *rt2 = (acmx / (*rt1)) * acmn - (b / (*rt1)) * b;
  } else {
    *rt1 = 0.5f * rt; *rt2 = -0.5f * rt; sgn1 = 1;
  }
  float cs; int sgn2;
  if (df >= 0.0f) { cs = df + rt; sgn2 = 1; } else { cs = df - rt; sgn2 = -1; }
  float acs = fabsf(cs), c1, s1;
  if (acs > ab) { float ct = -tb / cs; s1 = 1.0f / sqrtf(1.0f + ct * ct); c1 = ct * s1; }
  else {
    if (ab == 0.0f) { c1 = 1.0f; s1 = 0.0f; }
    else { float tn = -cs / tb; c1 = 1.0f / sqrtf(1.0f + tn * tn); s1 = tn * c1; }
  }
  if (sgn1 == sgn2) { float t = c1; c1 = -s1; s1 = t; }
  *cs1 = c1; *sn1 = s1;
}

// Faithful n=3 port of LAPACK ssteqr (COMPZ='I'; scaling path elided — our
// matrices have anorm well inside [ssfmin, ssfmax]). z must be identity on entry.
__device__ void steqr3(float* dd, float* ee, float z[3][3]) {
  const float eps = 5.9604645e-8f;
  const float eps2 = eps * eps;
  const float safmin = 1.17549435e-38f;
  const int nmaxit = 90;
  int jtot = 0;
  int l1 = 1, l = 0, lsv, lend, lendsv, m, i;
  float p, g, r, c, s, f, bb, rt1, rt2;
  float cw[2], sw2[2];

L10:
  if (l1 > 3) goto L160;
  if (l1 > 1) ee[l1 - 2] = 0.0f;
  if (l1 <= 2) {
    for (m = l1; m <= 2; ++m) {
      float tst = fabsf(ee[m - 1]);
      if (tst == 0.0f) goto L30;
      if (tst <= (sqrtf(fabsf(dd[m - 1])) * sqrtf(fabsf(dd[m]))) * eps) {
        ee[m - 1] = 0.0f; goto L30;
      }
    }
  }
  m = 3;
L30:
  l = l1; lsv = l; lend = m; lendsv = lend; l1 = m + 1;
  if (lend == l) goto L10;
  {
    float anorm = 0.0f;
    for (i = l; i <= lend; ++i)      anorm = fmaxf(anorm, fabsf(dd[i - 1]));
    for (i = l; i <= lend - 1; ++i)  anorm = fmaxf(anorm, fabsf(ee[i - 1]));
    if (anorm == 0.0f) goto L10;
  }
  if (fabsf(dd[lend - 1]) < fabsf(dd[l - 1])) { lend = lsv; l = lendsv; }

  if (lend > l) {
    // ---- QL iteration ----
L40:
    if (l != lend) {
      for (m = l; m <= lend - 1; ++m) {
        float tst = ee[m - 1] * ee[m - 1];
        if (tst <= (eps2 * fabsf(dd[m - 1])) * fabsf(dd[m]) + safmin) goto L60;
      }
    }
    m = lend;
L60:
    if (m < lend) ee[m - 1] = 0.0f;
    p = dd[l - 1];
    if (m == l) goto L80;
    if (m == l + 1) {
      laev2f(dd[l - 1], ee[l - 1], dd[l], &rt1, &rt2, &c, &s);
      // lasr 'R','V','B', single rotation on 1-idx cols (l, l+1)
      for (int i2 = 0; i2 < 3; ++i2) {
        float temp = z[i2][l];
        z[i2][l]     = c * temp - s * z[i2][l - 1];
        z[i2][l - 1] = s * temp + c * z[i2][l - 1];
      }
      dd[l - 1] = rt1; dd[l] = rt2; ee[l - 1] = 0.0f;
      l += 2;
      if (l <= lend) goto L40;
      goto L140;
    }
    if (jtot == nmaxit) goto L140;
    jtot++;
    g = (dd[l] - p) / (2.0f * ee[l - 1]);
    r = lapy2f(g, 1.0f);
    g = dd[m - 1] - p + ee[l - 1] / (g + copysignf(r, g));
    s = 1.0f; c = 1.0f; p = 0.0f;
    for (i = m - 1; i >= l; --i) {
      f = s * ee[i - 1]; bb = c * ee[i - 1];
      lartgf(g, f, &c, &s, &r);
      if (i != m - 1) ee[i] = r;
      g = dd[i] - p;
      r = (dd[i - 1] - g) * s + 2.0f * c * bb;
      p = s * r;
      dd[i] = g + p;
      g = c * r - bb;
      cw[i - 1] = c; sw2[i - 1] = -s;
    }
    for (int jj = m - 1; jj >= l; --jj) {   // lasr 'B'
      float ct = cw[jj - 1], st = sw2[jj - 1];
      for (int i2 = 0; i2 < 3; ++i2) {
        float temp = z[i2][jj];
        z[i2][jj]     = ct * temp - st * z[i2][jj - 1];
        z[i2][jj - 1] = st * temp + ct * z[i2][jj - 1];
      }
    }
    dd[l - 1] -= p;
    ee[l - 1] = g;
    goto L40;
L80:
    dd[l - 1] = p;
    l++;
    if (l <= lend) goto L40;
    goto L140;
  } else {
    // ---- QR iteration ----
L90:
    if (l != lend) {
      for (m = l; m >= lend + 1; --m) {
        float tst = ee[m - 2] * ee[m - 2];
        if (tst <= (eps2 * fabsf(dd[m - 1])) * fabsf(dd[m - 2]) + safmin) goto L110;
      }
    }
    m = lend;
L110:
    if (m > lend) ee[m - 2] = 0.0f;
    p = dd[l - 1];
    if (m == l) goto L130;
    if (m == l - 1) {
      laev2f(dd[l - 2], ee[l - 2], dd[l - 1], &rt1, &rt2, &c, &s);
      // lasr 'R','V','F', single rotation on 1-idx cols (l-1, l)
      for (int i2 = 0; i2 < 3; ++i2) {
        float temp = z[i2][l - 1];
        z[i2][l - 1] = c * temp - s * z[i2][l - 2];
        z[i2][l - 2] = s * temp + c * z[i2][l - 2];
      }
      dd[l - 2] = rt1; dd[l - 1] = rt2; ee[l - 2] = 0.0f;
      l -= 2;
      if (l >= lend) goto L90;
      goto L140;
    }
    if (jtot == nmaxit) goto L140;
    jtot++;
    g = (dd[l - 2] - p) / (2.0f * ee[l - 2]);
    r = lapy2f(g, 1.0f);
    g = dd[m - 1] - p + ee[l - 2] / (g + copysignf(r, g));
    s = 1.0f; c = 1.0f; p = 0.0f;
    for (i = m; i <= l - 1; ++i) {
      f = s * ee[i - 1]; bb = c * ee[i - 1];
      lartgf(g, f, &c, &s, &r);
      if (i != m) ee[i - 2] = r;
      g = dd[i - 1] - p;
      r = (dd[i] - g) * s + 2.0f * c * bb;
      p = s * r;
      dd[i - 1] = g + p;
      g = c * r - bb;
      cw[i - 1] = c; sw2[i - 1] = s;
    }
    for (int jj = m; jj <= l - 1; ++jj) {   // lasr 'F'
      float ct = cw[jj - 1], st = sw2[jj - 1];
      for (int i2 = 0; i2 < 3; ++i2) {
        float temp = z[i2][jj];
        z[i2][jj]     = ct * temp - st * z[i2][jj - 1];
        z[i2][jj - 1] = st * temp + ct * z[i2][jj - 1];
      }
    }
    dd[l - 1] -= p;
    ee[l - 2] = g;
    goto L90;
L130:
    dd[l - 1] = p;
    l--;
    if (l >= lend) goto L90;
    goto L140;
  }
L140:
  if (jtot < nmaxit) goto L10;
  return;  // max-iter (won't happen for SPD 3x3): LAPACK returns unsorted

L160:
  // selection sort ascending, swapping eigenvector columns
  for (int ii = 2; ii <= 3; ++ii) {
    int i0 = ii - 1, k0 = i0;
    p = dd[i0 - 1];
    for (int j = ii; j <= 3; ++j) {
      if (dd[j - 1] < p) { k0 = j; p = dd[j - 1]; }
    }
    if (k0 != i0) {
      dd[k0 - 1] = dd[i0 - 1]; dd[i0 - 1] = p;
      for (i = 0; i < 3; ++i) {
        float t = z[i][i0 - 1]; z[i][i0 - 1] = z[i][k0 - 1]; z[i][k0 - 1] = t;
      }
    }
  }
}

// ssyevd path for a 3x3 symmetric matrix: sytd2 (lower) -> steqr('I') -> apply Q
// A packed: a00,a01,a02,a11,a12,a22.  w ascending; z columns are eigenvectors.
__device__ void syevd3(const float* A, float* w, float z[3][3]) {
  float a00 = A[0], a01 = A[1], a02 = A[2], a11 = A[3], a12 = A[4], a22 = A[5];
  float d[3], e[2];
  float tau = 0.0f, v2 = 0.0f;

  float alpha = a01;
  float xnorm = fabsf(a02);
  if (xnorm == 0.0f) {
    tau = 0.0f; v2 = 0.0f;
    d[0] = a00; d[1] = a11; d[2] = a22; e[0] = a01; e[1] = a12;
  } else {
    float beta = -copysignf(lapy2f(alpha, xnorm), alpha);
    tau = (beta - alpha) / beta;
    v2  = a02 / (alpha - beta);
    float w1 = tau * (a11 + a12 * v2);
    float w2 = tau * (a12 + a22 * v2);
    float al = -0.5f * tau * (w1 + w2 * v2);
    w1 += al; w2 += al * v2;
    d[0] = a00;
    d[1] = a11 - w1 - w1;
    e[1] = a12 - w1 * v2 - w2;
    d[2] = a22 - v2 * w2 - w2 * v2;
    e[0] = beta;
  }

  for (int i = 0; i < 3; ++i)
    for (int j = 0; j < 3; ++j) z[i][j] = (i == j) ? 1.0f : 0.0f;

  steqr3(d, e, z);

  // Z := H * Z  (Householder on rows 1..2; Q from sytrd)
  if (tau != 0.0f) {
    for (int j = 0; j < 3; ++j) {
      float s = z[1][j] + v2 * z[2][j];
      z[1][j] = z[1][j] - tau * s;
      z[2][j] = z[2][j] - tau * v2 * s;
    }
  }
  w[0] = d[0]; w[1] = d[1]; w[2] = d[2];
}

// =====================================================================
__global__ __launch_bounds__(1024, 1)
void gmm_kernel(const float* __restrict__ xg, float* __restrict__ out) {
  const int b = blockIdx.x;
  const int tid = threadIdx.x;
  const int lane = tid & 63;
  const int wave = tid >> 6;
  const float* xb = xg + (size_t)b * (kN * 3);

  __shared__ float s_red[kWAVES * 160];
  __shared__ float s_mom[160];
  __shared__ float s_cst[kK][10];
  __shared__ float s_mean[kK][3];
  __shared__ float s_cov[kK][6];
  __shared__ float s_w[kK];
  __shared__ float s_Nk[kK];
  __shared__ float s_m0[3];
  __shared__ float s_var0;
  __shared__ float s_pt[3];
  __shared__ float s_val[kWAVES];
  __shared__ int   s_idx[kWAVES];

  // ---- load this thread's 16 points into registers
  float px[kNPT], py[kNPT], pz[kNPT];
#pragma unroll
  for (int p = 0; p < kNPT; ++p) {
    int n = tid + p * kTH;
    px[p] = xb[n * 3 + 0];
    py[p] = xb[n * 3 + 1];
    pz[p] = xb[n * 3 + 2];
  }

  // ---- m0 (uniform weights: plain mean)
  float sx = 0.f, sy = 0.f, sz = 0.f;
#pragma unroll
  for (int p = 0; p < kNPT; ++p) { sx += px[p]; sy += py[p]; sz += pz[p]; }
#pragma unroll
  for (int o = 32; o >= 1; o >>= 1) {
    sx += __shfl_xor(sx, o); sy += __shfl_xor(sy, o); sz += __shfl_xor(sz, o);
  }
  if (lane == 0) { s_red[wave] = sx; s_red[kWAVES + wave] = sy; s_red[2 * kWAVES + wave] = sz; }
  __syncthreads();
  if (tid == 0) {
    float a = 0.f, b2 = 0.f, c2 = 0.f;
    for (int w = 0; w < kWAVES; ++w) { a += s_red[w]; b2 += s_red[kWAVES + w]; c2 += s_red[2 * kWAVES + w]; }
    s_m0[0] = a / (float)kN; s_m0[1] = b2 / (float)kN; s_m0[2] = c2 / (float)kN;
  }
  __syncthreads();
  const float m00 = s_m0[0], m01 = s_m0[1], m02 = s_m0[2];

  // ---- var0
  float sv2 = 0.f;
#pragma unroll
  for (int p = 0; p < kNPT; ++p) {
    float dx = px[p] - m00, dy = py[p] - m01, dz = pz[p] - m02;
    sv2 += dx * dx + dy * dy + dz * dz;
  }
#pragma unroll
  for (int o = 32; o >= 1; o >>= 1) sv2 += __shfl_xor(sv2, o);
  if (lane == 0) s_red[wave] = sv2;
  __syncthreads();
  if (tid == 0) {
    float a = 0.f;
    for (int w = 0; w < kWAVES; ++w) a += s_red[w];
    s_var0 = a / (float)(3 * kN);
  }
  __syncthreads();
  const float var0 = s_var0;

  // ---- FPS (farthest point sampling), bit-matching the reference
  if (tid == 0) {
    s_pt[0] = xb[126]; s_pt[1] = xb[127]; s_pt[2] = xb[128];       // x[:, 42]
    s_mean[0][0] = xb[126]; s_mean[0][1] = xb[127]; s_mean[0][2] = xb[128];
  }
  __syncthreads();
  float d2[kNPT];
#pragma unroll
  for (int p = 0; p < kNPT; ++p)
    d2[p] = dist2nc(px[p], py[p], pz[p], s_pt[0], s_pt[1], s_pt[2]);

  for (int it = 1; it < kK; ++it) {
    float bv = -3.402823466e38f; int bi = 0x7fffffff;
#pragma unroll
    for (int p = 0; p < kNPT; ++p) {
      if (d2[p] > bv) { bv = d2[p]; bi = tid + p * kTH; }
    }
#pragma unroll
    for (int o = 32; o >= 1; o >>= 1) {
      float ov = __shfl_xor(bv, o);
      int   oi = __shfl_xor(bi, o);
      if (ov > bv || (ov == bv && oi < bi)) { bv = ov; bi = oi; }
    }
    if (lane == 0) { s_val[wave] = bv; s_idx[wave] = bi; }
    __syncthreads();
    if (tid == 0) {
      float gv = s_val[0]; int gi = s_idx[0];
      for (int w = 1; w < kWAVES; ++w) {
        float v = s_val[w]; int ii = s_idx[w];
        if (v > gv || (v == gv && ii < gi)) { gv = v; gi = ii; }
      }
      const float* pp = xb + (size_t)gi * 3;
      s_pt[0] = pp[0]; s_pt[1] = pp[1]; s_pt[2] = pp[2];
      s_mean[it][0] = pp[0]; s_mean[it][1] = pp[1]; s_mean[it][2] = pp[2];
    }
    __syncthreads();
#pragma unroll
    for (int p = 0; p < kNPT; ++p) {
      float nd = dist2nc(px[p], py[p], pz[p], s_pt[0], s_pt[1], s_pt[2]);
      d2[p] = fminf(d2[p], nd);
    }
  }

  // ---- init covs / weights
  if (tid < kK) {
    float gs2 = 0.09f * var0;
    s_cov[tid][0] = gs2; s_cov[tid][1] = 0.f; s_cov[tid][2] = 0.f;
    s_cov[tid][3] = gs2; s_cov[tid][4] = 0.f; s_cov[tid][5] = gs2;
    s_w[tid] = 0.0625f;
  }
  __syncthreads();

  // ---- EM (10 damped iterations)
  const float pwc = 0.0390625f;      // N_eff / N = 640/16384
  const float regv = 1e-4f * var0;
  for (int iter = 0; iter < 10; ++iter) {
    if (tid < kK) {
      int k = tid;
      float c00 = s_cov[k][0], c01 = s_cov[k][1], c02 = s_cov[k][2];
      float c11 = s_cov[k][3], c12 = s_cov[k][4], c22 = s_cov[k][5];
      float M0 = c11 * c22 - c12 * c12;
      float M1 = c01 * c22 - c12 * c02;
      float M2 = c01 * c12 - c11 * c02;
      float det = c00 * M0 - c01 * M1 + c02 * M2;
      float idet = 1.0f / det;
      float P00 = M0 * idet;
      float P01 = -M1 * idet;
      float P02 = M2 * idet;
      float P11 = (c00 * c22 - c02 * c02) * idet;
      float P12 = -(c00 * c12 - c02 * c01) * idet;
      float P22 = (c00 * c11 - c01 * c01) * idet;
      float logdet = logf(det);
      float mu0 = s_mean[k][0], mu1 = s_mean[k][1], mu2 = s_mean[k][2];
      float Pm0 = P00 * mu0 + P01 * mu1 + P02 * mu2;
      float Pm1 = P01 * mu0 + P11 * mu1 + P12 * mu2;
      float Pm2 = P02 * mu0 + P12 * mu1 + P22 * mu2;
      float muPmu = mu0 * Pm0 + mu1 * Pm1 + mu2 * Pm2;
      float gk = logf(s_w[k] + 1e-12f) - 0.5f * (muPmu + logdet + 3.0f * 1.8378770351409912f);
      s_cst[k][0] = -0.5f * P00; s_cst[k][1] = -0.5f * P11; s_cst[k][2] = -0.5f * P22;
      s_cst[k][3] = -P01; s_cst[k][4] = -P02; s_cst[k][5] = -P12;
      s_cst[k][6] = Pm0;  s_cst[k][7] = Pm1;  s_cst[k][8] = Pm2;
      s_cst[k][9] = gk;
    }
    __syncthreads();

    float cst[kK][10];
#pragma unroll
    for (int k = 0; k < kK; ++k)
#pragma unroll
      for (int j = 0; j < 10; ++j) cst[k][j] = s_cst[k][j];

    float acc[kK][10];
#pragma unroll
    for (int k = 0; k < kK; ++k)
#pragma unroll
      for (int j = 0; j < 10; ++j) acc[k][j] = 0.f;

#pragma unroll
    for (int p = 0; p < kNPT; ++p) {
      float x0 = px[p], x1 = py[p], x2 = pz[p];
      float q00 = x0 * x0, q11 = x1 * x1, q22 = x2 * x2;
      float q01 = x0 * x1, q02 = x0 * x2, q12 = x1 * x2;
      float svv[kK];
#pragma unroll
      for (int k = 0; k < kK; ++k) {
        float t = cst[k][9];
        t = fmaf(cst[k][0], q00, t);
        t = fmaf(cst[k][1], q11, t);
        t = fmaf(cst[k][2], q22, t);
        t = fmaf(cst[k][3], q01, t);
        t = fmaf(cst[k][4], q02, t);
        t = fmaf(cst[k][5], q12, t);
        t = fmaf(cst[k][6], x0, t);
        t = fmaf(cst[k][7], x1, t);
        t = fmaf(cst[k][8], x2, t);
        svv[k] = t;
      }
      float mx = svv[0];
#pragma unroll
      for (int k = 1; k < kK; ++k) mx = fmaxf(mx, svv[k]);
      float ssum = 0.f;
#pragma unroll
      for (int k = 0; k < kK; ++k) { float e = __expf(svv[k] - mx); svv[k] = e; ssum += e; }
      float inv = 1.0f / ssum;
#pragma unroll
      for (int k = 0; k < kK; ++k) {
        float r = svv[k] * inv;
        acc[k][0] += r;
        acc[k][1] = fmaf(r, x0, acc[k][1]);
        acc[k][2] = fmaf(r, x1, acc[k][2]);
        acc[k][3] = fmaf(r, x2, acc[k][3]);
        acc[k][4] = fmaf(r, q00, acc[k][4]);
        acc[k][5] = fmaf(r, q01, acc[k][5]);
        acc[k][6] = fmaf(r, q02, acc[k][6]);
        acc[k][7] = fmaf(r, q11, acc[k][7]);
        acc[k][8] = fmaf(r, q12, acc[k][8]);
        acc[k][9] = fmaf(r, q22, acc[k][9]);
      }
    }

    // wave butterfly reduce of the 160 moments
#pragma unroll
    for (int k = 0; k < kK; ++k)
#pragma unroll
      for (int j = 0; j < 10; ++j) {
        float v = acc[k][j];
#pragma unroll
        for (int o = 32; o >= 1; o >>= 1) v += __shfl_xor(v, o);
        acc[k][j] = v;
      }
    if (lane == 0) {
#pragma unroll
      for (int k = 0; k < kK; ++k)
#pragma unroll
        for (int j = 0; j < 10; ++j) s_red[wave * 160 + k * 10 + j] = acc[k][j];
    }
    __syncthreads();
    if (tid < 160) {
      float a = 0.f;
      for (int w = 0; w < kWAVES; ++w) a += s_red[w * 160 + tid];
      s_mom[tid] = a;
    }
    __syncthreads();

    // M-step
    if (tid < kK) {
      int k = tid;
      float Nk = pwc * s_mom[k * 10 + 0] + 1e-8f;
      float xb0 = pwc * s_mom[k * 10 + 1] / Nk;
      float xb1 = pwc * s_mom[k * 10 + 2] / Nk;
      float xb2 = pwc * s_mom[k * 10 + 3] / Nk;
      float E00 = pwc * s_mom[k * 10 + 4] / Nk;
      float E01 = pwc * s_mom[k * 10 + 5] / Nk;
      float E02 = pwc * s_mom[k * 10 + 6] / Nk;
      float E11 = pwc * s_mom[k * 10 + 7] / Nk;
      float E12 = pwc * s_mom[k * 10 + 8] / Nk;
      float E22 = pwc * s_mom[k * 10 + 9] / Nk;
      float S00 = E00 - xb0 * xb0, S01 = E01 - xb0 * xb1, S02 = E02 - xb0 * xb2;
      float S11 = E11 - xb1 * xb1, S12 = E12 - xb1 * xb2, S22 = E22 - xb2 * xb2;
      float dm0 = xb0 - m00, dm1 = xb1 - m01, dm2 = xb2 - m02;
      float coef = 1.0f / (1.0f + Nk);
      float cn00 = S00 + coef * (dm0 * dm0) + regv;
      float cn01 = S01 + coef * (dm0 * dm1);
      float cn02 = S02 + coef * (dm0 * dm2);
      float cn11 = S11 + coef * (dm1 * dm1) + regv;
      float cn12 = S12 + coef * (dm1 * dm2);
      float cn22 = S22 + coef * (dm2 * dm2) + regv;
      float bn = 1.0f + Nk;
      float mn0 = (m00 + Nk * xb0) / bn;
      float mn1 = (m01 + Nk * xb1) / bn;
      float mn2 = (m02 + Nk * xb2) / bn;
      s_mean[k][0] = 0.5f * s_mean[k][0] + 0.5f * mn0;
      s_mean[k][1] = 0.5f * s_mean[k][1] + 0.5f * mn1;
      s_mean[k][2] = 0.5f * s_mean[k][2] + 0.5f * mn2;
      s_cov[k][0] = 0.5f * s_cov[k][0] + 0.5f * cn00;
      s_cov[k][1] = 0.5f * s_cov[k][1] + 0.5f * cn01;
      s_cov[k][2] = 0.5f * s_cov[k][2] + 0.5f * cn02;
      s_cov[k][3] = 0.5f * s_cov[k][3] + 0.5f * cn11;
      s_cov[k][4] = 0.5f * s_cov[k][4] + 0.5f * cn12;
      s_cov[k][5] = 0.5f * s_cov[k][5] + 0.5f * cn22;
      s_Nk[k] = Nk;
    }
    __syncthreads();
    if (tid < kK) {
      float sN = 0.f;
      for (int j = 0; j < kK; ++j) sN += s_Nk[j];
      float wn = s_Nk[tid] / sN;
      s_w[tid] = 0.5f * s_w[tid] + 0.5f * wn;
    }
    __syncthreads();
  }

  // ---- eigh (LAPACK ssyevd port) + output
  if (tid < kK) {
    int k = tid;
    float A[6] = { s_cov[k][0], s_cov[k][1], s_cov[k][2],
                   s_cov[k][3], s_cov[k][4], s_cov[k][5] };
    float wv[3], Z[3][3];
    syevd3(A, wv, Z);
    const float thr = 0.01f * 640.0f / 16.0f;   // 0.01 * N_eff / K, f32 rounding as ref
    float valid = (s_Nk[k] > thr) ? 1.0f : 0.0f;
    float mu0 = s_mean[k][0], mu1 = s_mean[k][1], mu2 = s_mean[k][2];
    float sg0 = sqrtf(fmaxf(wv[0], 0.0f));
    float sg1 = sqrtf(fmaxf(wv[1], 0.0f));
    float sg2 = sqrtf(fmaxf(wv[2], 0.0f));
    float sgs[3] = { sg0, sg1, sg2 };
    float* po = out + ((size_t)b * 112 + k * 7) * 3;
    po[0] = mu0 * valid; po[1] = mu1 * valid; po[2] = mu2 * valid;
#pragma unroll
    for (int i2 = 0; i2 < 3; ++i2) {
      float sgi = sgs[i2];
      po[(1 + i2) * 3 + 0] = (mu0 + Z[0][i2] * sgi) * valid;
      po[(1 + i2) * 3 + 1] = (mu1 + Z[1][i2] * sgi) * valid;
      po[(1 + i2) * 3 + 2] = (mu2 + Z[2][i2] * sgi) * valid;
      po[(4 + i2) * 3 + 0] = (mu0 - Z[0][i2] * sgi) * valid;
      po[(4 + i2) * 3 + 1] = (mu1 - Z[1][i2] * sgi) * valid;
      po[(4 + i2) * 3 + 2] = (mu2 - Z[2][i2] * sgi) * valid;
    }
    float* vo = out + (size_t)kB * 112 * 3 + (size_t)b * 112 + k * 7;
#pragma unroll
    for (int j = 0; j < 7; ++j) vo[j] = valid;
  }
}

} // namespace

extern "C" void kernel_launch(void* const* d_in, const int* in_sizes, int n_in,
                              void* d_out, int out_size, void* d_ws, size_t ws_size,
                              hipStream_t stream) {
  const float* x = (const float*)d_in[0];
  float* out = (float*)d_out;
  gmm_kernel<<<dim3(kB), dim3(kTH), 0, stream>>>(x, out);
}

// Round 2
// 1339.132 us; speedup vs baseline: 3.2196x; 3.2196x over previous
//
#include <hip/hip_runtime.h>
#include <math.h>

namespace {

constexpr int kB    = 64;
constexpr int kN    = 16384;
constexpr int kK    = 16;
constexpr int kTH   = 256;    // threads per block (4 waves -> 1 wave/SIMD -> 512 VGPR budget)
constexpr int kCH   = 64;     // point-chunks per thread (kN / kTH)
constexpr int kWAVES = 4;

// ---------- exact (no-FMA) squared distance, matching XLA's sub/mul/add order ----------
__device__ __forceinline__ float dist2nc(float ax, float ay, float az,
                                         float bx, float by, float bz) {
#pragma clang fp contract(off)
  float dx = ax - bx;
  float dy = ay - by;
  float dz = az - bz;
  float s2 = dx * dx + dy * dy;
  return s2 + dz * dz;
}

// ---------- LAPACK helper ports (fp32) ----------
__device__ __forceinline__ float lapy2f(float x, float y) {
  float xa = fabsf(x), ya = fabsf(y);
  float w = fmaxf(xa, ya), z = fminf(xa, ya);
  if (z == 0.0f) return w;
  float t = z / w;
  return w * sqrtf(1.0f + t * t);
}

// LAPACK >= 3.10 slartg convention: c = |f|/r >= 0, r = sign(f)*hypot
__device__ __forceinline__ void lartgf(float f, float g, float* cs, float* sn, float* r) {
  if (g == 0.0f) { *cs = 1.0f; *sn = 0.0f; *r = f; }
  else if (f == 0.0f) { *cs = 0.0f; *sn = copysignf(1.0f, g); *r = fabsf(g); }
  else {
    float d = sqrtf(f * f + g * g);
    float p = 1.0f / d;
    *cs = fabsf(f) * p;
    *sn = g * copysignf(p, f);
    *r  = copysignf(d, f);
  }
}

// slaev2: eigen decomposition of [[a,b],[b,c]]; rt1 >= rt2, (cs1,sn1) for rt1
__device__ void laev2f(float a, float b, float c,
                       float* rt1, float* rt2, float* cs1, float* sn1) {
  float sm = a + c, df = a - c;
  float adf = fabsf(df), tb = b + b, ab = fabsf(tb);
  float acmx, acmn;
  if (fabsf(a) > fabsf(c)) { acmx = a; acmn = c; } else { acmx = c; acmn = a; }
  float rt;
  if (adf > ab)      { float t = ab / adf; rt = adf * sqrtf(1.0f + t * t); }
  else if (adf < ab) { float t = adf / ab; rt = ab * sqrtf(1.0f + t * t); }
  else               { rt = ab * sqrtf(2.0f); }
  int sgn1;
  if (sm < 0.0f) {
    *rt1 = 0.5f * (sm - rt); sgn1 = -1;
    *rt2 = (acmx / (*rt1)) * acmn - (b / (*rt1)) * b;
  } else if (sm > 0.0f) {
    *rt1 = 0.5f * (sm + rt); sgn1 = 1;
    *rt2 = (acmx / (*rt1)) * acmn - (b / (*rt1)) * b;
  } else {
    *rt1 = 0.5f * rt; *rt2 = -0.5f * rt; sgn1 = 1;
  }
  float cs; int sgn2;
  if (df >= 0.0f) { cs = df + rt; sgn2 = 1; } else { cs = df - rt; sgn2 = -1; }
  float acs = fabsf(cs), c1, s1;
  if (acs > ab) { float ct = -tb / cs; s1 = 1.0f / sqrtf(1.0f + ct * ct); c1 = ct * s1; }
  else {
    if (ab == 0.0f) { c1 = 1.0f; s1 = 0.0f; }
    else { float tn = -cs / tb; c1 = 1.0f / sqrtf(1.0f + tn * tn); s1 = tn * c1; }
  }
  if (sgn1 == sgn2) { float t = c1; c1 = -s1; s1 = t; }
  *cs1 = c1; *sn1 = s1;
}

// Faithful n=3 port of LAPACK ssteqr (COMPZ='I'). z must be identity on entry.
__device__ void steqr3(float* dd, float* ee, float z[3][3]) {
  const float eps = 5.9604645e-8f;
  const float eps2 = eps * eps;
  const float safmin = 1.17549435e-38f;
  const int nmaxit = 90;
  int jtot = 0;
  int l1 = 1, l = 0, lsv, lend, lendsv, m, i;
  float p, g, r, c, s, f, bb, rt1, rt2;
  float cw[2], sw2[2];

L10:
  if (l1 > 3) goto L160;
  if (l1 > 1) ee[l1 - 2] = 0.0f;
  if (l1 <= 2) {
    for (m = l1; m <= 2; ++m) {
      float tst = fabsf(ee[m - 1]);
      if (tst == 0.0f) goto L30;
      if (tst <= (sqrtf(fabsf(dd[m - 1])) * sqrtf(fabsf(dd[m]))) * eps) {
        ee[m - 1] = 0.0f; goto L30;
      }
    }
  }
  m = 3;
L30:
  l = l1; lsv = l; lend = m; lendsv = lend; l1 = m + 1;
  if (lend == l) goto L10;
  {
    float anorm = 0.0f;
    for (i = l; i <= lend; ++i)      anorm = fmaxf(anorm, fabsf(dd[i - 1]));
    for (i = l; i <= lend - 1; ++i)  anorm = fmaxf(anorm, fabsf(ee[i - 1]));
    if (anorm == 0.0f) goto L10;
  }
  if (fabsf(dd[lend - 1]) < fabsf(dd[l - 1])) { lend = lsv; l = lendsv; }

  if (lend > l) {
L40:
    if (l != lend) {
      for (m = l; m <= lend - 1; ++m) {
        float tst = ee[m - 1] * ee[m - 1];
        if (tst <= (eps2 * fabsf(dd[m - 1])) * fabsf(dd[m]) + safmin) goto L60;
      }
    }
    m = lend;
L60:
    if (m < lend) ee[m - 1] = 0.0f;
    p = dd[l - 1];
    if (m == l) goto L80;
    if (m == l + 1) {
      laev2f(dd[l - 1], ee[l - 1], dd[l], &rt1, &rt2, &c, &s);
      for (int i2 = 0; i2 < 3; ++i2) {
        float temp = z[i2][l];
        z[i2][l]     = c * temp - s * z[i2][l - 1];
        z[i2][l - 1] = s * temp + c * z[i2][l - 1];
      }
      dd[l - 1] = rt1; dd[l] = rt2; ee[l - 1] = 0.0f;
      l += 2;
      if (l <= lend) goto L40;
      goto L140;
    }
    if (jtot == nmaxit) goto L140;
    jtot++;
    g = (dd[l] - p) / (2.0f * ee[l - 1]);
    r = lapy2f(g, 1.0f);
    g = dd[m - 1] - p + ee[l - 1] / (g + copysignf(r, g));
    s = 1.0f; c = 1.0f; p = 0.0f;
    for (i = m - 1; i >= l; --i) {
      f = s * ee[i - 1]; bb = c * ee[i - 1];
      lartgf(g, f, &c, &s, &r);
      if (i != m - 1) ee[i] = r;
      g = dd[i] - p;
      r = (dd[i - 1] - g) * s + 2.0f * c * bb;
      p = s * r;
      dd[i] = g + p;
      g = c * r - bb;
      cw[i - 1] = c; sw2[i - 1] = -s;
    }
    for (int jj = m - 1; jj >= l; --jj) {
      float ct = cw[jj - 1], st = sw2[jj - 1];
      for (int i2 = 0; i2 < 3; ++i2) {
        float temp = z[i2][jj];
        z[i2][jj]     = ct * temp - st * z[i2][jj - 1];
        z[i2][jj - 1] = st * temp + ct * z[i2][jj - 1];
      }
    }
    dd[l - 1] -= p;
    ee[l - 1] = g;
    goto L40;
L80:
    dd[l - 1] = p;
    l++;
    if (l <= lend) goto L40;
    goto L140;
  } else {
L90:
    if (l != lend) {
      for (m = l; m >= lend + 1; --m) {
        float tst = ee[m - 2] * ee[m - 2];
        if (tst <= (eps2 * fabsf(dd[m - 1])) * fabsf(dd[m - 2]) + safmin) goto L110;
      }
    }
    m = lend;
L110:
    if (m > lend) ee[m - 2] = 0.0f;
    p = dd[l - 1];
    if (m == l) goto L130;
    if (m == l - 1) {
      laev2f(dd[l - 2], ee[l - 2], dd[l - 1], &rt1, &rt2, &c, &s);
      for (int i2 = 0; i2 < 3; ++i2) {
        float temp = z[i2][l - 1];
        z[i2][l - 1] = c * temp - s * z[i2][l - 2];
        z[i2][l - 2] = s * temp + c * z[i2][l - 2];
      }
      dd[l - 2] = rt1; dd[l - 1] = rt2; ee[l - 2] = 0.0f;
      l -= 2;
      if (l >= lend) goto L90;
      goto L140;
    }
    if (jtot == nmaxit) goto L140;
    jtot++;
    g = (dd[l - 2] - p) / (2.0f * ee[l - 2]);
    r = lapy2f(g, 1.0f);
    g = dd[m - 1] - p + ee[l - 2] / (g + copysignf(r, g));
    s = 1.0f; c = 1.0f; p = 0.0f;
    for (i = m; i <= l - 1; ++i) {
      f = s * ee[i - 1]; bb = c * ee[i - 1];
      lartgf(g, f, &c, &s, &r);
      if (i != m) ee[i - 2] = r;
      g = dd[i - 1] - p;
      r = (dd[i] - g) * s + 2.0f * c * bb;
      p = s * r;
      dd[i - 1] = g + p;
      g = c * r - bb;
      cw[i - 1] = c; sw2[i - 1] = s;
    }
    for (int jj = m; jj <= l - 1; ++jj) {
      float ct = cw[jj - 1], st = sw2[jj - 1];
      for (int i2 = 0; i2 < 3; ++i2) {
        float temp = z[i2][jj];
        z[i2][jj]     = ct * temp - st * z[i2][jj - 1];
        z[i2][jj - 1] = st * temp + ct * z[i2][jj - 1];
      }
    }
    dd[l - 1] -= p;
    ee[l - 2] = g;
    goto L90;
L130:
    dd[l - 1] = p;
    l--;
    if (l >= lend) goto L90;
    goto L140;
  }
L140:
  if (jtot < nmaxit) goto L10;
  return;

L160:
  for (int ii = 2; ii <= 3; ++ii) {
    int i0 = ii - 1, k0 = i0;
    p = dd[i0 - 1];
    for (int j = ii; j <= 3; ++j) {
      if (dd[j - 1] < p) { k0 = j; p = dd[j - 1]; }
    }
    if (k0 != i0) {
      dd[k0 - 1] = dd[i0 - 1]; dd[i0 - 1] = p;
      for (i = 0; i < 3; ++i) {
        float t = z[i][i0 - 1]; z[i][i0 - 1] = z[i][k0 - 1]; z[i][k0 - 1] = t;
      }
    }
  }
}

// ssyevd path for a 3x3 symmetric matrix: sytd2 (lower) -> steqr('I') -> apply Q
__device__ void syevd3(const float* A, float* w, float z[3][3]) {
  float a00 = A[0], a01 = A[1], a02 = A[2], a11 = A[3], a12 = A[4], a22 = A[5];
  float d[3], e[2];
  float tau = 0.0f, v2 = 0.0f;

  float alpha = a01;
  float xnorm = fabsf(a02);
  if (xnorm == 0.0f) {
    tau = 0.0f; v2 = 0.0f;
    d[0] = a00; d[1] = a11; d[2] = a22; e[0] = a01; e[1] = a12;
  } else {
    float beta = -copysignf(lapy2f(alpha, xnorm), alpha);
    tau = (beta - alpha) / beta;
    v2  = a02 / (alpha - beta);
    float w1 = tau * (a11 + a12 * v2);
    float w2 = tau * (a12 + a22 * v2);
    float al = -0.5f * tau * (w1 + w2 * v2);
    w1 += al; w2 += al * v2;
    d[0] = a00;
    d[1] = a11 - w1 - w1;
    e[1] = a12 - w1 * v2 - w2;
    d[2] = a22 - v2 * w2 - w2 * v2;
    e[0] = beta;
  }

  for (int i = 0; i < 3; ++i)
    for (int j = 0; j < 3; ++j) z[i][j] = (i == j) ? 1.0f : 0.0f;

  steqr3(d, e, z);

  if (tau != 0.0f) {
    for (int j = 0; j < 3; ++j) {
      float s = z[1][j] + v2 * z[2][j];
      z[1][j] = z[1][j] - tau * s;
      z[2][j] = z[2][j] - tau * v2 * s;
    }
  }
  w[0] = d[0]; w[1] = d[1]; w[2] = d[2];
}

// =====================================================================
// 256 threads/block (1 wave/SIMD): full 512-VGPR budget per thread, so
// cst[16][10] + acc[16][10] stay in registers (the round-1 spill source).
// Points are streamed from global (L2-resident, 196 KB/block) every pass.
__global__ __launch_bounds__(kTH, 1)
void gmm_kernel(const float* __restrict__ xg, float* __restrict__ out) {
  const int b = blockIdx.x;
  const int tid = threadIdx.x;
  const int lane = tid & 63;
  const int wave = tid >> 6;
  const float* xb = xg + (size_t)b * (kN * 3);

  __shared__ float s_red[kWAVES * 160];
  __shared__ float s_mom[160];
  __shared__ float s_cst[kK][10];
  __shared__ float s_mean[kK][3];
  __shared__ float s_cov[kK][6];
  __shared__ float s_w[kK];
  __shared__ float s_Nk[kK];
  __shared__ float s_m0[3];
  __shared__ float s_var0;
  __shared__ float s_pt[3];
  __shared__ float s_val[kWAVES];
  __shared__ int   s_idx[kWAVES];

  // ---- m0 (uniform weights: plain mean) — streamed
  float sx = 0.f, sy = 0.f, sz = 0.f;
#pragma unroll 8
  for (int c = 0; c < kCH; ++c) {
    int n = c * kTH + tid;
    sx += xb[3 * n + 0]; sy += xb[3 * n + 1]; sz += xb[3 * n + 2];
  }
#pragma unroll
  for (int o = 32; o >= 1; o >>= 1) {
    sx += __shfl_xor(sx, o); sy += __shfl_xor(sy, o); sz += __shfl_xor(sz, o);
  }
  if (lane == 0) { s_red[wave] = sx; s_red[kWAVES + wave] = sy; s_red[2 * kWAVES + wave] = sz; }
  __syncthreads();
  if (tid == 0) {
    float a = 0.f, b2 = 0.f, c2 = 0.f;
    for (int w = 0; w < kWAVES; ++w) { a += s_red[w]; b2 += s_red[kWAVES + w]; c2 += s_red[2 * kWAVES + w]; }
    s_m0[0] = a / (float)kN; s_m0[1] = b2 / (float)kN; s_m0[2] = c2 / (float)kN;
  }
  __syncthreads();
  const float m00 = s_m0[0], m01 = s_m0[1], m02 = s_m0[2];

  // ---- var0 — streamed
  float sv2 = 0.f;
#pragma unroll 8
  for (int c = 0; c < kCH; ++c) {
    int n = c * kTH + tid;
    float dx = xb[3 * n + 0] - m00, dy = xb[3 * n + 1] - m01, dz = xb[3 * n + 2] - m02;
    sv2 += dx * dx + dy * dy + dz * dz;
  }
#pragma unroll
  for (int o = 32; o >= 1; o >>= 1) sv2 += __shfl_xor(sv2, o);
  if (lane == 0) s_red[wave] = sv2;
  __syncthreads();
  if (tid == 0) {
    float a = 0.f;
    for (int w = 0; w < kWAVES; ++w) a += s_red[w];
    s_var0 = a / (float)(3 * kN);
  }
  __syncthreads();
  const float var0 = s_var0;

  // ---- FPS (farthest point sampling), bit-matching the reference.
  // d2[64] stays in registers; x is re-streamed per step (identical values ->
  // identical argmax decisions).
  if (tid == 0) {
    s_pt[0] = xb[126]; s_pt[1] = xb[127]; s_pt[2] = xb[128];       // x[:, 42]
    s_mean[0][0] = xb[126]; s_mean[0][1] = xb[127]; s_mean[0][2] = xb[128];
  }
  __syncthreads();
  float d2[kCH];
  {
    float ax = s_pt[0], ay = s_pt[1], az = s_pt[2];
#pragma unroll 8
    for (int c = 0; c < kCH; ++c) {
      int n = c * kTH + tid;
      d2[c] = dist2nc(xb[3 * n + 0], xb[3 * n + 1], xb[3 * n + 2], ax, ay, az);
    }
  }

  for (int it = 1; it < kK; ++it) {
    float bv = -3.402823466e38f; int bi = 0x7fffffff;
#pragma unroll
    for (int c = 0; c < kCH; ++c) {
      if (d2[c] > bv) { bv = d2[c]; bi = c * kTH + tid; }
    }
#pragma unroll
    for (int o = 32; o >= 1; o >>= 1) {
      float ov = __shfl_xor(bv, o);
      int   oi = __shfl_xor(bi, o);
      if (ov > bv || (ov == bv && oi < bi)) { bv = ov; bi = oi; }
    }
    if (lane == 0) { s_val[wave] = bv; s_idx[wave] = bi; }
    __syncthreads();
    if (tid == 0) {
      float gv = s_val[0]; int gi = s_idx[0];
      for (int w = 1; w < kWAVES; ++w) {
        float v = s_val[w]; int ii = s_idx[w];
        if (v > gv || (v == gv && ii < gi)) { gv = v; gi = ii; }
      }
      const float* pp = xb + (size_t)gi * 3;
      s_pt[0] = pp[0]; s_pt[1] = pp[1]; s_pt[2] = pp[2];
      s_mean[it][0] = pp[0]; s_mean[it][1] = pp[1]; s_mean[it][2] = pp[2];
    }
    __syncthreads();
    {
      float ax = s_pt[0], ay = s_pt[1], az = s_pt[2];
#pragma unroll 8
      for (int c = 0; c < kCH; ++c) {
        int n = c * kTH + tid;
        float nd = dist2nc(xb[3 * n + 0], xb[3 * n + 1], xb[3 * n + 2], ax, ay, az);
        d2[c] = fminf(d2[c], nd);
      }
    }
  }

  // ---- init covs / weights
  if (tid < kK) {
    float gs2 = 0.09f * var0;
    s_cov[tid][0] = gs2; s_cov[tid][1] = 0.f; s_cov[tid][2] = 0.f;
    s_cov[tid][3] = gs2; s_cov[tid][4] = 0.f; s_cov[tid][5] = gs2;
    s_w[tid] = 0.0625f;
  }
  __syncthreads();

  // ---- EM (10 damped iterations)
  const float pwc = 0.0390625f;      // N_eff / N = 640/16384
  const float regv = 1e-4f * var0;
  for (int iter = 0; iter < 10; ++iter) {
    if (tid < kK) {
      int k = tid;
      float c00 = s_cov[k][0], c01 = s_cov[k][1], c02 = s_cov[k][2];
      float c11 = s_cov[k][3], c12 = s_cov[k][4], c22 = s_cov[k][5];
      float M0 = c11 * c22 - c12 * c12;
      float M1 = c01 * c22 - c12 * c02;
      float M2 = c01 * c12 - c11 * c02;
      float det = c00 * M0 - c01 * M1 + c02 * M2;
      float idet = 1.0f / det;
      float P00 = M0 * idet;
      float P01 = -M1 * idet;
      float P02 = M2 * idet;
      float P11 = (c00 * c22 - c02 * c02) * idet;
      float P12 = -(c00 * c12 - c02 * c01) * idet;
      float P22 = (c00 * c11 - c01 * c01) * idet;
      float logdet = logf(det);
      float mu0 = s_mean[k][0], mu1 = s_mean[k][1], mu2 = s_mean[k][2];
      float Pm0 = P00 * mu0 + P01 * mu1 + P02 * mu2;
      float Pm1 = P01 * mu0 + P11 * mu1 + P12 * mu2;
      float Pm2 = P02 * mu0 + P12 * mu1 + P22 * mu2;
      float muPmu = mu0 * Pm0 + mu1 * Pm1 + mu2 * Pm2;
      float gk = logf(s_w[k] + 1e-12f) - 0.5f * (muPmu + logdet + 3.0f * 1.8378770351409912f);
      s_cst[k][0] = -0.5f * P00; s_cst[k][1] = -0.5f * P11; s_cst[k][2] = -0.5f * P22;
      s_cst[k][3] = -P01; s_cst[k][4] = -P02; s_cst[k][5] = -P12;
      s_cst[k][6] = Pm0;  s_cst[k][7] = Pm1;  s_cst[k][8] = Pm2;
      s_cst[k][9] = gk;
    }
    __syncthreads();

    float cst[kK][10];
#pragma unroll
    for (int k = 0; k < kK; ++k)
#pragma unroll
      for (int j = 0; j < 10; ++j) cst[k][j] = s_cst[k][j];

    float acc[kK][10];
#pragma unroll
    for (int k = 0; k < kK; ++k)
#pragma unroll
      for (int j = 0; j < 10; ++j) acc[k][j] = 0.f;

    // streamed E-step: 2-point chunks with one-chunk software prefetch
    float Xc[2][3];
#pragma unroll
    for (int j = 0; j < 2; ++j) {
      int n = j * kTH + tid;
      Xc[j][0] = xb[3 * n + 0]; Xc[j][1] = xb[3 * n + 1]; Xc[j][2] = xb[3 * n + 2];
    }
    for (int c = 0; c < kCH; c += 2) {
      float Xn[2][3];
      if (c + 2 < kCH) {
#pragma unroll
        for (int j = 0; j < 2; ++j) {
          int n = (c + 2 + j) * kTH + tid;
          Xn[j][0] = xb[3 * n + 0]; Xn[j][1] = xb[3 * n + 1]; Xn[j][2] = xb[3 * n + 2];
        }
      }
#pragma unroll
      for (int j = 0; j < 2; ++j) {
        float x0 = Xc[j][0], x1 = Xc[j][1], x2 = Xc[j][2];
        float q00 = x0 * x0, q11 = x1 * x1, q22 = x2 * x2;
        float q01 = x0 * x1, q02 = x0 * x2, q12 = x1 * x2;
        float svv[kK];
#pragma unroll
        for (int k = 0; k < kK; ++k) {
          float t = cst[k][9];
          t = fmaf(cst[k][0], q00, t);
          t = fmaf(cst[k][1], q11, t);
          t = fmaf(cst[k][2], q22, t);
          t = fmaf(cst[k][3], q01, t);
          t = fmaf(cst[k][4], q02, t);
          t = fmaf(cst[k][5], q12, t);
          t = fmaf(cst[k][6], x0, t);
          t = fmaf(cst[k][7], x1, t);
          t = fmaf(cst[k][8], x2, t);
          svv[k] = t;
        }
        float mx = svv[0];
#pragma unroll
        for (int k = 1; k < kK; ++k) mx = fmaxf(mx, svv[k]);
        float ssum = 0.f;
#pragma unroll
        for (int k = 0; k < kK; ++k) { float e = __expf(svv[k] - mx); svv[k] = e; ssum += e; }
        float inv = 1.0f / ssum;
#pragma unroll
        for (int k = 0; k < kK; ++k) {
          float r = svv[k] * inv;
          acc[k][0] += r;
          acc[k][1] = fmaf(r, x0, acc[k][1]);
          acc[k][2] = fmaf(r, x1, acc[k][2]);
          acc[k][3] = fmaf(r, x2, acc[k][3]);
          acc[k][4] = fmaf(r, q00, acc[k][4]);
          acc[k][5] = fmaf(r, q01, acc[k][5]);
          acc[k][6] = fmaf(r, q02, acc[k][6]);
          acc[k][7] = fmaf(r, q11, acc[k][7]);
          acc[k][8] = fmaf(r, q12, acc[k][8]);
          acc[k][9] = fmaf(r, q22, acc[k][9]);
        }
      }
#pragma unroll
      for (int j = 0; j < 2; ++j) {
        Xc[j][0] = Xn[j][0]; Xc[j][1] = Xn[j][1]; Xc[j][2] = Xn[j][2];
      }
    }

    // wave butterfly reduce of the 160 moments
#pragma unroll
    for (int k = 0; k < kK; ++k)
#pragma unroll
      for (int j = 0; j < 10; ++j) {
        float v = acc[k][j];
#pragma unroll
        for (int o = 32; o >= 1; o >>= 1) v += __shfl_xor(v, o);
        acc[k][j] = v;
      }
    if (lane == 0) {
#pragma unroll
      for (int k = 0; k < kK; ++k)
#pragma unroll
        for (int j = 0; j < 10; ++j) s_red[wave * 160 + k * 10 + j] = acc[k][j];
    }
    __syncthreads();
    if (tid < 160) {
      float a = 0.f;
      for (int w = 0; w < kWAVES; ++w) a += s_red[w * 160 + tid];
      s_mom[tid] = a;
    }
    __syncthreads();

    // M-step
    if (tid < kK) {
      int k = tid;
      float Nk = pwc * s_mom[k * 10 + 0] + 1e-8f;
      float xb0 = pwc * s_mom[k * 10 + 1] / Nk;
      float xb1 = pwc * s_mom[k * 10 + 2] / Nk;
      float xb2 = pwc * s_mom[k * 10 + 3] / Nk;
      float E00 = pwc * s_mom[k * 10 + 4] / Nk;
      float E01 = pwc * s_mom[k * 10 + 5] / Nk;
      float E02 = pwc * s_mom[k * 10 + 6] / Nk;
      float E11 = pwc * s_mom[k * 10 + 7] / Nk;
      float E12 = pwc * s_mom[k * 10 + 8] / Nk;
      float E22 = pwc * s_mom[k * 10 + 9] / Nk;
      float S00 = E00 - xb0 * xb0, S01 = E01 - xb0 * xb1, S02 = E02 - xb0 * xb2;
      float S11 = E11 - xb1 * xb1, S12 = E12 - xb1 * xb2, S22 = E22 - xb2 * xb2;
      float dm0 = xb0 - m00, dm1 = xb1 - m01, dm2 = xb2 - m02;
      float coef = 1.0f / (1.0f + Nk);
      float cn00 = S00 + coef * (dm0 * dm0) + regv;
      float cn01 = S01 + coef * (dm0 * dm1);
      float cn02 = S02 + coef * (dm0 * dm2);
      float cn11 = S11 + coef * (dm1 * dm1) + regv;
      float cn12 = S12 + coef * (dm1 * dm2);
      float cn22 = S22 + coef * (dm2 * dm2) + regv;
      float bn = 1.0f + Nk;
      float mn0 = (m00 + Nk * xb0) / bn;
      float mn1 = (m01 + Nk * xb1) / bn;
      float mn2 = (m02 + Nk * xb2) / bn;
      s_mean[k][0] = 0.5f * s_mean[k][0] + 0.5f * mn0;
      s_mean[k][1] = 0.5f * s_mean[k][1] + 0.5f * mn1;
      s_mean[k][2] = 0.5f * s_mean[k][2] + 0.5f * mn2;
      s_cov[k][0] = 0.5f * s_cov[k][0] + 0.5f * cn00;
      s_cov[k][1] = 0.5f * s_cov[k][1] + 0.5f * cn01;
      s_cov[k][2] = 0.5f * s_cov[k][2] + 0.5f * cn02;
      s_cov[k][3] = 0.5f * s_cov[k][3] + 0.5f * cn11;
      s_cov[k][4] = 0.5f * s_cov[k][4] + 0.5f * cn12;
      s_cov[k][5] = 0.5f * s_cov[k][5] + 0.5f * cn22;
      s_Nk[k] = Nk;
    }
    __syncthreads();
    if (tid < kK) {
      float sN = 0.f;
      for (int j = 0; j < kK; ++j) sN += s_Nk[j];
      float wn = s_Nk[tid] / sN;
      s_w[tid] = 0.5f * s_w[tid] + 0.5f * wn;
    }
    __syncthreads();
  }

  // ---- eigh (LAPACK ssyevd port) + output
  if (tid < kK) {
    int k = tid;
    float A[6] = { s_cov[k][0], s_cov[k][1], s_cov[k][2],
                   s_cov[k][3], s_cov[k][4], s_cov[k][5] };
    float wv[3], Z[3][3];
    syevd3(A, wv, Z);
    const float thr = 0.01f * 640.0f / 16.0f;   // 0.01 * N_eff / K
    float valid = (s_Nk[k] > thr) ? 1.0f : 0.0f;
    float mu0 = s_mean[k][0], mu1 = s_mean[k][1], mu2 = s_mean[k][2];
    float sg0 = sqrtf(fmaxf(wv[0], 0.0f));
    float sg1 = sqrtf(fmaxf(wv[1], 0.0f));
    float sg2 = sqrtf(fmaxf(wv[2], 0.0f));
    float sgs[3] = { sg0, sg1, sg2 };
    float* po = out + ((size_t)b * 112 + k * 7) * 3;
    po[0] = mu0 * valid; po[1] = mu1 * valid; po[2] = mu2 * valid;
#pragma unroll
    for (int i2 = 0; i2 < 3; ++i2) {
      float sgi = sgs[i2];
      po[(1 + i2) * 3 + 0] = (mu0 + Z[0][i2] * sgi) * valid;
      po[(1 + i2) * 3 + 1] = (mu1 + Z[1][i2] * sgi) * valid;
      po[(1 + i2) * 3 + 2] = (mu2 + Z[2][i2] * sgi) * valid;
      po[(4 + i2) * 3 + 0] = (mu0 - Z[0][i2] * sgi) * valid;
      po[(4 + i2) * 3 + 1] = (mu1 - Z[1][i2] * sgi) * valid;
      po[(4 + i2) * 3 + 2] = (mu2 - Z[2][i2] * sgi) * valid;
    }
    float* vo = out + (size_t)kB * 112 * 3 + (size_t)b * 112 + k * 7;
#pragma unroll
    for (int j = 0; j < 7; ++j) vo[j] = valid;
  }
}

} // namespace

extern "C" void kernel_launch(void* const* d_in, const int* in_sizes, int n_in,
                              void* d_out, int out_size, void* d_ws, size_t ws_size,
                              hipStream_t stream) {
  const float* x = (const float*)d_in[0];
  float* out = (float*)d_out;
  gmm_kernel<<<dim3(kB), dim3(kTH), 0, stream>>>(x, out);
}

// Round 3
// 430.860 us; speedup vs baseline: 10.0067x; 3.1080x over previous
//
#include <hip/hip_runtime.h>
#include <math.h>

namespace {

constexpr int kB    = 64;
constexpr int kN    = 16384;
constexpr int kK    = 16;
constexpr int kSUB  = 4;        // E-step blocks per batch
constexpr int kETH  = 256;      // E-step threads/block
constexpr int kEPT  = 16;       // points per E-thread (kN/kSUB/kETH)

// workspace layout (floats)
constexpr int WS_M0    = 0;                    // [64][4]: m0x,m0y,m0z,var0
constexpr int WS_STATE = 256;                  // [64][160]: mean[48], cov[96], w[16]
constexpr int WS_PART  = 256 + 64 * 160;       // [64*4][160] partial moments
// total = 256 + 10240 + 40960 = 51456 floats (~206 KB)

// ---------- exact (no-FMA) squared distance, matching XLA's op order ----------
__device__ __forceinline__ float dist2nc(float ax, float ay, float az,
                                         float bx, float by, float bz) {
#pragma clang fp contract(off)
  float dx = ax - bx;
  float dy = ay - by;
  float dz = az - bz;
  float s2 = dx * dx + dy * dy;
  return s2 + dz * dz;
}

// ---------- LAPACK helper ports (fp32) ----------
__device__ __forceinline__ float lapy2f(float x, float y) {
  float xa = fabsf(x), ya = fabsf(y);
  float w = fmaxf(xa, ya), z = fminf(xa, ya);
  if (z == 0.0f) return w;
  float t = z / w;
  return w * sqrtf(1.0f + t * t);
}

__device__ __forceinline__ void lartgf(float f, float g, float* cs, float* sn, float* r) {
  if (g == 0.0f) { *cs = 1.0f; *sn = 0.0f; *r = f; }
  else if (f == 0.0f) { *cs = 0.0f; *sn = copysignf(1.0f, g); *r = fabsf(g); }
  else {
    float d = sqrtf(f * f + g * g);
    float p = 1.0f / d;
    *cs = fabsf(f) * p;
    *sn = g * copysignf(p, f);
    *r  = copysignf(d, f);
  }
}

__device__ void laev2f(float a, float b, float c,
                       float* rt1, float* rt2, float* cs1, float* sn1) {
  float sm = a + c, df = a - c;
  float adf = fabsf(df), tb = b + b, ab = fabsf(tb);
  float acmx, acmn;
  if (fabsf(a) > fabsf(c)) { acmx = a; acmn = c; } else { acmx = c; acmn = a; }
  float rt;
  if (adf > ab)      { float t = ab / adf; rt = adf * sqrtf(1.0f + t * t); }
  else if (adf < ab) { float t = adf / ab; rt = ab * sqrtf(1.0f + t * t); }
  else               { rt = ab * sqrtf(2.0f); }
  int sgn1;
  if (sm < 0.0f) {
    *rt1 = 0.5f * (sm - rt); sgn1 = -1;
    *rt2 = (acmx / (*rt1)) * acmn - (b / (*rt1)) * b;
  } else if (sm > 0.0f) {
    *rt1 = 0.5f * (sm + rt); sgn1 = 1;
    *rt2 = (acmx / (*rt1)) * acmn - (b / (*rt1)) * b;
  } else {
    *rt1 = 0.5f * rt; *rt2 = -0.5f * rt; sgn1 = 1;
  }
  float cs; int sgn2;
  if (df >= 0.0f) { cs = df + rt; sgn2 = 1; } else { cs = df - rt; sgn2 = -1; }
  float acs = fabsf(cs), c1, s1;
  if (acs > ab) { float ct = -tb / cs; s1 = 1.0f / sqrtf(1.0f + ct * ct); c1 = ct * s1; }
  else {
    if (ab == 0.0f) { c1 = 1.0f; s1 = 0.0f; }
    else { float tn = -cs / tb; c1 = 1.0f / sqrtf(1.0f + tn * tn); s1 = tn * c1; }
  }
  if (sgn1 == sgn2) { float t = c1; c1 = -s1; s1 = t; }
  *cs1 = c1; *sn1 = s1;
}

// Faithful n=3 port of LAPACK ssteqr (COMPZ='I'). z identity on entry.
__device__ void steqr3(float* dd, float* ee, float z[3][3]) {
  const float eps = 5.9604645e-8f;
  const float eps2 = eps * eps;
  const float safmin = 1.17549435e-38f;
  const int nmaxit = 90;
  int jtot = 0;
  int l1 = 1, l = 0, lsv, lend, lendsv, m, i;
  float p, g, r, c, s, f, bb, rt1, rt2;
  float cw[2], sw2[2];

L10:
  if (l1 > 3) goto L160;
  if (l1 > 1) ee[l1 - 2] = 0.0f;
  if (l1 <= 2) {
    for (m = l1; m <= 2; ++m) {
      float tst = fabsf(ee[m - 1]);
      if (tst == 0.0f) goto L30;
      if (tst <= (sqrtf(fabsf(dd[m - 1])) * sqrtf(fabsf(dd[m]))) * eps) {
        ee[m - 1] = 0.0f; goto L30;
      }
    }
  }
  m = 3;
L30:
  l = l1; lsv = l; lend = m; lendsv = lend; l1 = m + 1;
  if (lend == l) goto L10;
  {
    float anorm = 0.0f;
    for (i = l; i <= lend; ++i)      anorm = fmaxf(anorm, fabsf(dd[i - 1]));
    for (i = l; i <= lend - 1; ++i)  anorm = fmaxf(anorm, fabsf(ee[i - 1]));
    if (anorm == 0.0f) goto L10;
  }
  if (fabsf(dd[lend - 1]) < fabsf(dd[l - 1])) { lend = lsv; l = lendsv; }

  if (lend > l) {
L40:
    if (l != lend) {
      for (m = l; m <= lend - 1; ++m) {
        float tst = ee[m - 1] * ee[m - 1];
        if (tst <= (eps2 * fabsf(dd[m - 1])) * fabsf(dd[m]) + safmin) goto L60;
      }
    }
    m = lend;
L60:
    if (m < lend) ee[m - 1] = 0.0f;
    p = dd[l - 1];
    if (m == l) goto L80;
    if (m == l + 1) {
      laev2f(dd[l - 1], ee[l - 1], dd[l], &rt1, &rt2, &c, &s);
      for (int i2 = 0; i2 < 3; ++i2) {
        float temp = z[i2][l];
        z[i2][l]     = c * temp - s * z[i2][l - 1];
        z[i2][l - 1] = s * temp + c * z[i2][l - 1];
      }
      dd[l - 1] = rt1; dd[l] = rt2; ee[l - 1] = 0.0f;
      l += 2;
      if (l <= lend) goto L40;
      goto L140;
    }
    if (jtot == nmaxit) goto L140;
    jtot++;
    g = (dd[l] - p) / (2.0f * ee[l - 1]);
    r = lapy2f(g, 1.0f);
    g = dd[m - 1] - p + ee[l - 1] / (g + copysignf(r, g));
    s = 1.0f; c = 1.0f; p = 0.0f;
    for (i = m - 1; i >= l; --i) {
      f = s * ee[i - 1]; bb = c * ee[i - 1];
      lartgf(g, f, &c, &s, &r);
      if (i != m - 1) ee[i] = r;
      g = dd[i] - p;
      r = (dd[i - 1] - g) * s + 2.0f * c * bb;
      p = s * r;
      dd[i] = g + p;
      g = c * r - bb;
      cw[i - 1] = c; sw2[i - 1] = -s;
    }
    for (int jj = m - 1; jj >= l; --jj) {
      float ct = cw[jj - 1], st = sw2[jj - 1];
      for (int i2 = 0; i2 < 3; ++i2) {
        float temp = z[i2][jj];
        z[i2][jj]     = ct * temp - st * z[i2][jj - 1];
        z[i2][jj - 1] = st * temp + ct * z[i2][jj - 1];
      }
    }
    dd[l - 1] -= p;
    ee[l - 1] = g;
    goto L40;
L80:
    dd[l - 1] = p;
    l++;
    if (l <= lend) goto L40;
    goto L140;
  } else {
L90:
    if (l != lend) {
      for (m = l; m >= lend + 1; --m) {
        float tst = ee[m - 2] * ee[m - 2];
        if (tst <= (eps2 * fabsf(dd[m - 1])) * fabsf(dd[m - 2]) + safmin) goto L110;
      }
    }
    m = lend;
L110:
    if (m > lend) ee[m - 2] = 0.0f;
    p = dd[l - 1];
    if (m == l) goto L130;
    if (m == l - 1) {
      laev2f(dd[l - 2], ee[l - 2], dd[l - 1], &rt1, &rt2, &c, &s);
      for (int i2 = 0; i2 < 3; ++i2) {
        float temp = z[i2][l - 1];
        z[i2][l - 1] = c * temp - s * z[i2][l - 2];
        z[i2][l - 2] = s * temp + c * z[i2][l - 2];
      }
      dd[l - 2] = rt1; dd[l - 1] = rt2; ee[l - 2] = 0.0f;
      l -= 2;
      if (l >= lend) goto L90;
      goto L140;
    }
    if (jtot == nmaxit) goto L140;
    jtot++;
    g = (dd[l - 2] - p) / (2.0f * ee[l - 2]);
    r = lapy2f(g, 1.0f);
    g = dd[m - 1] - p + ee[l - 2] / (g + copysignf(r, g));
    s = 1.0f; c = 1.0f; p = 0.0f;
    for (i = m; i <= l - 1; ++i) {
      f = s * ee[i - 1]; bb = c * ee[i - 1];
      lartgf(g, f, &c, &s, &r);
      if (i != m) ee[i - 2] = r;
      g = dd[i - 1] - p;
      r = (dd[i] - g) * s + 2.0f * c * bb;
      p = s * r;
      dd[i - 1] = g + p;
      g = c * r - bb;
      cw[i - 1] = c; sw2[i - 1] = s;
    }
    for (int jj = m; jj <= l - 1; ++jj) {
      float ct = cw[jj - 1], st = sw2[jj - 1];
      for (int i2 = 0; i2 < 3; ++i2) {
        float temp = z[i2][jj];
        z[i2][jj]     = ct * temp - st * z[i2][jj - 1];
        z[i2][jj - 1] = st * temp + ct * z[i2][jj - 1];
      }
    }
    dd[l - 1] -= p;
    ee[l - 2] = g;
    goto L90;
L130:
    dd[l - 1] = p;
    l--;
    if (l >= lend) goto L90;
    goto L140;
  }
L140:
  if (jtot < nmaxit) goto L10;
  return;

L160:
  for (int ii = 2; ii <= 3; ++ii) {
    int i0 = ii - 1, k0 = i0;
    p = dd[i0 - 1];
    for (int j = ii; j <= 3; ++j) {
      if (dd[j - 1] < p) { k0 = j; p = dd[j - 1]; }
    }
    if (k0 != i0) {
      dd[k0 - 1] = dd[i0 - 1]; dd[i0 - 1] = p;
      for (i = 0; i < 3; ++i) {
        float t = z[i][i0 - 1]; z[i][i0 - 1] = z[i][k0 - 1]; z[i][k0 - 1] = t;
      }
    }
  }
}

__device__ void syevd3(const float* A, float* w, float z[3][3]) {
  float a00 = A[0], a01 = A[1], a02 = A[2], a11 = A[3], a12 = A[4], a22 = A[5];
  float d[3], e[2];
  float tau = 0.0f, v2 = 0.0f;

  float alpha = a01;
  float xnorm = fabsf(a02);
  if (xnorm == 0.0f) {
    tau = 0.0f; v2 = 0.0f;
    d[0] = a00; d[1] = a11; d[2] = a22; e[0] = a01; e[1] = a12;
  } else {
    float beta = -copysignf(lapy2f(alpha, xnorm), alpha);
    tau = (beta - alpha) / beta;
    v2  = a02 / (alpha - beta);
    float w1 = tau * (a11 + a12 * v2);
    float w2 = tau * (a12 + a22 * v2);
    float al = -0.5f * tau * (w1 + w2 * v2);
    w1 += al; w2 += al * v2;
    d[0] = a00;
    d[1] = a11 - w1 - w1;
    e[1] = a12 - w1 * v2 - w2;
    d[2] = a22 - v2 * w2 - w2 * v2;
    e[0] = beta;
  }

  for (int i = 0; i < 3; ++i)
    for (int j = 0; j < 3; ++j) z[i][j] = (i == j) ? 1.0f : 0.0f;

  steqr3(d, e, z);

  if (tau != 0.0f) {
    for (int j = 0; j < 3; ++j) {
      float s = z[1][j] + v2 * z[2][j];
      z[1][j] = z[1][j] - tau * s;
      z[2][j] = z[2][j] - tau * v2 * s;
    }
  }
  w[0] = d[0]; w[1] = d[1]; w[2] = d[2];
}

// =====================================================================
// Kernel 1: per-batch m0/var0 + bit-exact FPS. 64 blocks x 1024 threads.
__global__ __launch_bounds__(1024, 1)
void setup_fps_kernel(const float* __restrict__ xg, float* __restrict__ ws) {
  const int b = blockIdx.x;
  const int tid = threadIdx.x;
  const int lane = tid & 63;
  const int wave = tid >> 6;
  const float* xb = xg + (size_t)b * (kN * 3);
  float* st = ws + WS_STATE + b * 160;

  __shared__ float s_redx[16], s_redy[16], s_redz[16];
  __shared__ float s_m0[3];
  __shared__ float s_var0;
  __shared__ float s_pt[3];
  __shared__ float s_val[16];
  __shared__ int   s_idx[16];

  // ---- m0
  float sx = 0.f, sy = 0.f, sz = 0.f;
#pragma unroll 4
  for (int c = 0; c < 16; ++c) {
    int n = c * 1024 + tid;
    sx += xb[3 * n + 0]; sy += xb[3 * n + 1]; sz += xb[3 * n + 2];
  }
#pragma unroll
  for (int o = 32; o >= 1; o >>= 1) {
    sx += __shfl_xor(sx, o); sy += __shfl_xor(sy, o); sz += __shfl_xor(sz, o);
  }
  if (lane == 0) { s_redx[wave] = sx; s_redy[wave] = sy; s_redz[wave] = sz; }
  __syncthreads();
  if (tid == 0) {
    float a = 0.f, b2 = 0.f, c2 = 0.f;
    for (int w = 0; w < 16; ++w) { a += s_redx[w]; b2 += s_redy[w]; c2 += s_redz[w]; }
    s_m0[0] = a / (float)kN; s_m0[1] = b2 / (float)kN; s_m0[2] = c2 / (float)kN;
  }
  __syncthreads();
  const float m00 = s_m0[0], m01 = s_m0[1], m02 = s_m0[2];

  // ---- var0
  float sv2 = 0.f;
#pragma unroll 4
  for (int c = 0; c < 16; ++c) {
    int n = c * 1024 + tid;
    float dx = xb[3 * n + 0] - m00, dy = xb[3 * n + 1] - m01, dz = xb[3 * n + 2] - m02;
    sv2 += dx * dx + dy * dy + dz * dz;
  }
#pragma unroll
  for (int o = 32; o >= 1; o >>= 1) sv2 += __shfl_xor(sv2, o);
  if (lane == 0) s_redx[wave] = sv2;
  __syncthreads();
  if (tid == 0) {
    float a = 0.f;
    for (int w = 0; w < 16; ++w) a += s_redx[w];
    s_var0 = a / (float)(3 * kN);
    ws[WS_M0 + b * 4 + 0] = m00;
    ws[WS_M0 + b * 4 + 1] = m01;
    ws[WS_M0 + b * 4 + 2] = m02;
    ws[WS_M0 + b * 4 + 3] = s_var0;
  }

  // ---- FPS (bit-matching the reference)
  if (tid == 0) {
    s_pt[0] = xb[126]; s_pt[1] = xb[127]; s_pt[2] = xb[128];       // x[:, 42]
    st[0] = xb[126]; st[1] = xb[127]; st[2] = xb[128];
  }
  __syncthreads();
  float d2[16];
  {
    float ax = s_pt[0], ay = s_pt[1], az = s_pt[2];
#pragma unroll 4
    for (int c = 0; c < 16; ++c) {
      int n = c * 1024 + tid;
      d2[c] = dist2nc(xb[3 * n + 0], xb[3 * n + 1], xb[3 * n + 2], ax, ay, az);
    }
  }

  for (int it = 1; it < kK; ++it) {
    float bv = -3.402823466e38f; int bi = 0x7fffffff;
#pragma unroll
    for (int c = 0; c < 16; ++c) {
      if (d2[c] > bv) { bv = d2[c]; bi = c * 1024 + tid; }
    }
#pragma unroll
    for (int o = 32; o >= 1; o >>= 1) {
      float ov = __shfl_xor(bv, o);
      int   oi = __shfl_xor(bi, o);
      if (ov > bv || (ov == bv && oi < bi)) { bv = ov; bi = oi; }
    }
    if (lane == 0) { s_val[wave] = bv; s_idx[wave] = bi; }
    __syncthreads();
    if (tid == 0) {
      float gv = s_val[0]; int gi = s_idx[0];
      for (int w = 1; w < 16; ++w) {
        float v = s_val[w]; int ii = s_idx[w];
        if (v > gv || (v == gv && ii < gi)) { gv = v; gi = ii; }
      }
      const float* pp = xb + (size_t)gi * 3;
      s_pt[0] = pp[0]; s_pt[1] = pp[1]; s_pt[2] = pp[2];
      st[it * 3 + 0] = pp[0]; st[it * 3 + 1] = pp[1]; st[it * 3 + 2] = pp[2];
    }
    __syncthreads();
    if (it < kK - 1) {
      float ax = s_pt[0], ay = s_pt[1], az = s_pt[2];
#pragma unroll 4
      for (int c = 0; c < 16; ++c) {
        int n = c * 1024 + tid;
        float nd = dist2nc(xb[3 * n + 0], xb[3 * n + 1], xb[3 * n + 2], ax, ay, az);
        d2[c] = fminf(d2[c], nd);
      }
    }
  }
}

// =====================================================================
// Kernel 2 (x10): inline M-step (redundant per block) + E-step partials.
// 256 blocks (4 per batch) x 256 threads, 1 block/CU, full VGPR budget.
__global__ __launch_bounds__(kETH, 1)
void em_step_kernel(const float* __restrict__ xg, float* __restrict__ ws, int iter) {
  const int batch = blockIdx.x >> 2;
  const int sub = blockIdx.x & 3;
  const int tid = threadIdx.x;
  const int lane = tid & 63;
  const int wave = tid >> 6;
  const float* xb = xg + (size_t)batch * (kN * 3);
  float* st = ws + WS_STATE + batch * 160;
  float* part = ws + WS_PART + (size_t)(batch * kSUB) * 160;

  __shared__ float s_cst[kK][10];
  __shared__ float s_Nk[kK];
  __shared__ float s_red[4 * 160];

  const float m00 = ws[WS_M0 + batch * 4 + 0];
  const float m01 = ws[WS_M0 + batch * 4 + 1];
  const float m02 = ws[WS_M0 + batch * 4 + 2];
  const float var0 = ws[WS_M0 + batch * 4 + 3];
  const float pwc = 0.0390625f;
  const float regv = 1e-4f * var0;

  // ---- Stage A: state for this iteration (computed redundantly per block)
  float mu0, mu1, mu2, c00, c01, c02, c11, c12, c22, wk;
  if (tid < kK) {
    int k = tid;
    if (iter == 0) {
      mu0 = st[k * 3 + 0]; mu1 = st[k * 3 + 1]; mu2 = st[k * 3 + 2];
      float gs2 = 0.09f * var0;
      c00 = gs2; c01 = 0.f; c02 = 0.f; c11 = gs2; c12 = 0.f; c22 = gs2;
      wk = 0.0625f;
    } else {
      // previous state
      float mp0 = st[k * 3 + 0], mp1 = st[k * 3 + 1], mp2 = st[k * 3 + 2];
      float cp0 = st[48 + k * 6 + 0], cp1 = st[48 + k * 6 + 1], cp2 = st[48 + k * 6 + 2];
      float cp3 = st[48 + k * 6 + 3], cp4 = st[48 + k * 6 + 4], cp5 = st[48 + k * 6 + 5];
      float wp = st[144 + k];
      // reduce prev-iteration partials (fixed order)
      float mom[10];
#pragma unroll
      for (int j = 0; j < 10; ++j) {
        float a = part[0 * 160 + k * 10 + j];
        a += part[1 * 160 + k * 10 + j];
        a += part[2 * 160 + k * 10 + j];
        a += part[3 * 160 + k * 10 + j];
        mom[j] = a;
      }
      float Nk = pwc * mom[0] + 1e-8f;
      float xb0 = pwc * mom[1] / Nk;
      float xb1 = pwc * mom[2] / Nk;
      float xb2 = pwc * mom[3] / Nk;
      float E00 = pwc * mom[4] / Nk;
      float E01 = pwc * mom[5] / Nk;
      float E02 = pwc * mom[6] / Nk;
      float E11 = pwc * mom[7] / Nk;
      float E12 = pwc * mom[8] / Nk;
      float E22 = pwc * mom[9] / Nk;
      float S00 = E00 - xb0 * xb0, S01 = E01 - xb0 * xb1, S02 = E02 - xb0 * xb2;
      float S11 = E11 - xb1 * xb1, S12 = E12 - xb1 * xb2, S22 = E22 - xb2 * xb2;
      float dm0 = xb0 - m00, dm1 = xb1 - m01, dm2 = xb2 - m02;
      float coef = 1.0f / (1.0f + Nk);
      float cn00 = S00 + coef * (dm0 * dm0) + regv;
      float cn01 = S01 + coef * (dm0 * dm1);
      float cn02 = S02 + coef * (dm0 * dm2);
      float cn11 = S11 + coef * (dm1 * dm1) + regv;
      float cn12 = S12 + coef * (dm1 * dm2);
      float cn22 = S22 + coef * (dm2 * dm2) + regv;
      float bn = 1.0f + Nk;
      float mn0 = (m00 + Nk * xb0) / bn;
      float mn1 = (m01 + Nk * xb1) / bn;
      float mn2 = (m02 + Nk * xb2) / bn;
      mu0 = 0.5f * mp0 + 0.5f * mn0;
      mu1 = 0.5f * mp1 + 0.5f * mn1;
      mu2 = 0.5f * mp2 + 0.5f * mn2;
      c00 = 0.5f * cp0 + 0.5f * cn00;
      c01 = 0.5f * cp1 + 0.5f * cn01;
      c02 = 0.5f * cp2 + 0.5f * cn02;
      c11 = 0.5f * cp3 + 0.5f * cn11;
      c12 = 0.5f * cp4 + 0.5f * cn12;
      c22 = 0.5f * cp5 + 0.5f * cn22;
      s_Nk[k] = Nk;
      wk = wp;           // updated after sync with sN
    }
  }
  __syncthreads();
  if (tid < kK && iter > 0) {
    float sN = 0.f;
    for (int j = 0; j < kK; ++j) sN += s_Nk[j];
    wk = 0.5f * wk + 0.5f * (s_Nk[tid] / sN);
  }
  // ---- cst from state
  if (tid < kK) {
    int k = tid;
    float M0 = c11 * c22 - c12 * c12;
    float M1 = c01 * c22 - c12 * c02;
    float M2 = c01 * c12 - c11 * c02;
    float det = c00 * M0 - c01 * M1 + c02 * M2;
    float idet = 1.0f / det;
    float P00 = M0 * idet;
    float P01 = -M1 * idet;
    float P02 = M2 * idet;
    float P11 = (c00 * c22 - c02 * c02) * idet;
    float P12 = -(c00 * c12 - c02 * c01) * idet;
    float P22 = (c00 * c11 - c01 * c01) * idet;
    float logdet = logf(det);
    float Pm0 = P00 * mu0 + P01 * mu1 + P02 * mu2;
    float Pm1 = P01 * mu0 + P11 * mu1 + P12 * mu2;
    float Pm2 = P02 * mu0 + P12 * mu1 + P22 * mu2;
    float muPmu = mu0 * Pm0 + mu1 * Pm1 + mu2 * Pm2;
    float gk = logf(wk + 1e-12f) - 0.5f * (muPmu + logdet + 3.0f * 1.8378770351409912f);
    s_cst[k][0] = -0.5f * P00; s_cst[k][1] = -0.5f * P11; s_cst[k][2] = -0.5f * P22;
    s_cst[k][3] = -P01; s_cst[k][4] = -P02; s_cst[k][5] = -P12;
    s_cst[k][6] = Pm0;  s_cst[k][7] = Pm1;  s_cst[k][8] = Pm2;
    s_cst[k][9] = gk;
    // persist state for next kernel (one block per batch)
    if (sub == 0) {
      st[k * 3 + 0] = mu0; st[k * 3 + 1] = mu1; st[k * 3 + 2] = mu2;
      st[48 + k * 6 + 0] = c00; st[48 + k * 6 + 1] = c01; st[48 + k * 6 + 2] = c02;
      st[48 + k * 6 + 3] = c11; st[48 + k * 6 + 4] = c12; st[48 + k * 6 + 5] = c22;
      st[144 + k] = wk;
    }
  }
  __syncthreads();

  // ---- Stage B: E-step over this block's 4096 points
  float cst[kK][10];
#pragma unroll
  for (int k = 0; k < kK; ++k)
#pragma unroll
    for (int j = 0; j < 10; ++j) cst[k][j] = s_cst[k][j];

  float acc[kK][10];
#pragma unroll
  for (int k = 0; k < kK; ++k)
#pragma unroll
    for (int j = 0; j < 10; ++j) acc[k][j] = 0.f;

  const int base = sub * (kN / kSUB) + tid;
  float cx = xb[3 * base + 0], cy = xb[3 * base + 1], cz = xb[3 * base + 2];
#pragma unroll 2
  for (int c = 0; c < kEPT; ++c) {
    float nx = 0.f, ny = 0.f, nz = 0.f;
    if (c + 1 < kEPT) {
      int n = base + (c + 1) * kETH;
      nx = xb[3 * n + 0]; ny = xb[3 * n + 1]; nz = xb[3 * n + 2];
    }
    float x0 = cx, x1 = cy, x2 = cz;
    float q00 = x0 * x0, q11 = x1 * x1, q22 = x2 * x2;
    float q01 = x0 * x1, q02 = x0 * x2, q12 = x1 * x2;
    float svv[kK];
#pragma unroll
    for (int k = 0; k < kK; ++k) {
      float t = cst[k][9];
      t = fmaf(cst[k][0], q00, t);
      t = fmaf(cst[k][1], q11, t);
      t = fmaf(cst[k][2], q22, t);
      t = fmaf(cst[k][3], q01, t);
      t = fmaf(cst[k][4], q02, t);
      t = fmaf(cst[k][5], q12, t);
      t = fmaf(cst[k][6], x0, t);
      t = fmaf(cst[k][7], x1, t);
      t = fmaf(cst[k][8], x2, t);
      svv[k] = t;
    }
    float mx = svv[0];
#pragma unroll
    for (int k = 1; k < kK; ++k) mx = fmaxf(mx, svv[k]);
    float ssum = 0.f;
#pragma unroll
    for (int k = 0; k < kK; ++k) { float e = __expf(svv[k] - mx); svv[k] = e; ssum += e; }
    float inv = 1.0f / ssum;
#pragma unroll
    for (int k = 0; k < kK; ++k) {
      float r = svv[k] * inv;
      acc[k][0] += r;
      acc[k][1] = fmaf(r, x0, acc[k][1]);
      acc[k][2] = fmaf(r, x1, acc[k][2]);
      acc[k][3] = fmaf(r, x2, acc[k][3]);
      acc[k][4] = fmaf(r, q00, acc[k][4]);
      acc[k][5] = fmaf(r, q01, acc[k][5]);
      acc[k][6] = fmaf(r, q02, acc[k][6]);
      acc[k][7] = fmaf(r, q11, acc[k][7]);
      acc[k][8] = fmaf(r, q12, acc[k][8]);
      acc[k][9] = fmaf(r, q22, acc[k][9]);
    }
    cx = nx; cy = ny; cz = nz;
  }

  // block reduce: wave butterfly then 4-wave sum
#pragma unroll
  for (int k = 0; k < kK; ++k)
#pragma unroll
    for (int j = 0; j < 10; ++j) {
      float v = acc[k][j];
#pragma unroll
      for (int o = 32; o >= 1; o >>= 1) v += __shfl_xor(v, o);
      acc[k][j] = v;
    }
  if (lane == 0) {
#pragma unroll
    for (int k = 0; k < kK; ++k)
#pragma unroll
      for (int j = 0; j < 10; ++j) s_red[wave * 160 + k * 10 + j] = acc[k][j];
  }
  __syncthreads();
  if (tid < 160) {
    float a = s_red[0 * 160 + tid];
    a += s_red[1 * 160 + tid];
    a += s_red[2 * 160 + tid];
    a += s_red[3 * 160 + tid];
    part[(size_t)sub * 160 + tid] = a;
  }
}

// =====================================================================
// Kernel 3: final M-step + eigh (one cluster per wave) + output.
__global__ __launch_bounds__(1024, 1)
void finalize_kernel(float* __restrict__ ws, float* __restrict__ out) {
  const int b = blockIdx.x;
  const int tid = threadIdx.x;
  const int lane = tid & 63;
  const int wave = tid >> 6;
  float* st = ws + WS_STATE + b * 160;
  const float* part = ws + WS_PART + (size_t)(b * kSUB) * 160;

  __shared__ float s_mean[kK][3];
  __shared__ float s_cov[kK][6];
  __shared__ float s_Nk[kK];

  const float m00 = ws[WS_M0 + b * 4 + 0];
  const float m01 = ws[WS_M0 + b * 4 + 1];
  const float m02 = ws[WS_M0 + b * 4 + 2];
  const float var0 = ws[WS_M0 + b * 4 + 3];
  const float pwc = 0.0390625f;
  const float regv = 1e-4f * var0;

  if (tid < kK) {
    int k = tid;
    float mp0 = st[k * 3 + 0], mp1 = st[k * 3 + 1], mp2 = st[k * 3 + 2];
    float cp0 = st[48 + k * 6 + 0], cp1 = st[48 + k * 6 + 1], cp2 = st[48 + k * 6 + 2];
    float cp3 = st[48 + k * 6 + 3], cp4 = st[48 + k * 6 + 4], cp5 = st[48 + k * 6 + 5];
    float mom[10];
#pragma unroll
    for (int j = 0; j < 10; ++j) {
      float a = part[0 * 160 + k * 10 + j];
      a += part[1 * 160 + k * 10 + j];
      a += part[2 * 160 + k * 10 + j];
      a += part[3 * 160 + k * 10 + j];
      mom[j] = a;
    }
    float Nk = pwc * mom[0] + 1e-8f;
    float xb0 = pwc * mom[1] / Nk;
    float xb1 = pwc * mom[2] / Nk;
    float xb2 = pwc * mom[3] / Nk;
    float E00 = pwc * mom[4] / Nk;
    float E01 = pwc * mom[5] / Nk;
    float E02 = pwc * mom[6] / Nk;
    float E11 = pwc * mom[7] / Nk;
    float E12 = pwc * mom[8] / Nk;
    float E22 = pwc * mom[9] / Nk;
    float S00 = E00 - xb0 * xb0, S01 = E01 - xb0 * xb1, S02 = E02 - xb0 * xb2;
    float S11 = E11 - xb1 * xb1, S12 = E12 - xb1 * xb2, S22 = E22 - xb2 * xb2;
    float dm0 = xb0 - m00, dm1 = xb1 - m01, dm2 = xb2 - m02;
    float coef = 1.0f / (1.0f + Nk);
    float cn00 = S00 + coef * (dm0 * dm0) + regv;
    float cn01 = S01 + coef * (dm0 * dm1);
    float cn02 = S02 + coef * (dm0 * dm2);
    float cn11 = S11 + coef * (dm1 * dm1) + regv;
    float cn12 = S12 + coef * (dm1 * dm2);
    float cn22 = S22 + coef * (dm2 * dm2) + regv;
    float bn = 1.0f + Nk;
    float mn0 = (m00 + Nk * xb0) / bn;
    float mn1 = (m01 + Nk * xb1) / bn;
    float mn2 = (m02 + Nk * xb2) / bn;
    s_mean[k][0] = 0.5f * mp0 + 0.5f * mn0;
    s_mean[k][1] = 0.5f * mp1 + 0.5f * mn1;
    s_mean[k][2] = 0.5f * mp2 + 0.5f * mn2;
    s_cov[k][0] = 0.5f * cp0 + 0.5f * cn00;
    s_cov[k][1] = 0.5f * cp1 + 0.5f * cn01;
    s_cov[k][2] = 0.5f * cp2 + 0.5f * cn02;
    s_cov[k][3] = 0.5f * cp3 + 0.5f * cn11;
    s_cov[k][4] = 0.5f * cp4 + 0.5f * cn12;
    s_cov[k][5] = 0.5f * cp5 + 0.5f * cn22;
    s_Nk[k] = Nk;
  }
  __syncthreads();

  // one cluster per wave (lane 0) so divergent steqr3 paths run in parallel
  if (lane == 0 && wave < kK) {
    int k = wave;
    float A[6] = { s_cov[k][0], s_cov[k][1], s_cov[k][2],
                   s_cov[k][3], s_cov[k][4], s_cov[k][5] };
    float wv[3], Z[3][3];
    syevd3(A, wv, Z);
    const float thr = 0.01f * 640.0f / 16.0f;
    float valid = (s_Nk[k] > thr) ? 1.0f : 0.0f;
    float mu0 = s_mean[k][0], mu1 = s_mean[k][1], mu2 = s_mean[k][2];
    float sgs[3] = { sqrtf(fmaxf(wv[0], 0.0f)),
                     sqrtf(fmaxf(wv[1], 0.0f)),
                     sqrtf(fmaxf(wv[2], 0.0f)) };
    float* po = out + ((size_t)b * 112 + k * 7) * 3;
    po[0] = mu0 * valid; po[1] = mu1 * valid; po[2] = mu2 * valid;
#pragma unroll
    for (int i2 = 0; i2 < 3; ++i2) {
      float sgi = sgs[i2];
      po[(1 + i2) * 3 + 0] = (mu0 + Z[0][i2] * sgi) * valid;
      po[(1 + i2) * 3 + 1] = (mu1 + Z[1][i2] * sgi) * valid;
      po[(1 + i2) * 3 + 2] = (mu2 + Z[2][i2] * sgi) * valid;
      po[(4 + i2) * 3 + 0] = (mu0 - Z[0][i2] * sgi) * valid;
      po[(4 + i2) * 3 + 1] = (mu1 - Z[1][i2] * sgi) * valid;
      po[(4 + i2) * 3 + 2] = (mu2 - Z[2][i2] * sgi) * valid;
    }
    float* vo = out + (size_t)kB * 112 * 3 + (size_t)b * 112 + k * 7;
#pragma unroll
    for (int j = 0; j < 7; ++j) vo[j] = valid;
  }
}

} // namespace

extern "C" void kernel_launch(void* const* d_in, const int* in_sizes, int n_in,
                              void* d_out, int out_size, void* d_ws, size_t ws_size,
                              hipStream_t stream) {
  const float* x = (const float*)d_in[0];
  float* out = (float*)d_out;
  float* ws = (float*)d_ws;

  setup_fps_kernel<<<dim3(kB), dim3(1024), 0, stream>>>(x, ws);
  for (int it = 0; it < 10; ++it)
    em_step_kernel<<<dim3(kB * kSUB), dim3(kETH), 0, stream>>>(x, ws, it);
  finalize_kernel<<<dim3(kB), dim3(1024), 0, stream>>>(ws, out);
}